// Round 4
// baseline (364.137 us; speedup 1.0000x reference)
//
#include <hip/hip_runtime.h>
#include <hip/hip_bf16.h>
#include <cstdint>

#define NN 50000
#define NE 1200000
#define DD 128
#define RR 6
#define NEG 0.2f

typedef __hip_bfloat16 bf16;
typedef __attribute__((ext_vector_type(8))) short short8;
typedef __attribute__((ext_vector_type(4))) float f32x4;

__device__ __forceinline__ float bflo(unsigned u) { return __uint_as_float((u & 0xFFFFu) << 16); }
__device__ __forceinline__ float bfhi(unsigned u) { return __uint_as_float(u & 0xFFFF0000u); }
__device__ __forceinline__ ushort f2b(float v) {  // f32 -> bf16 RTNE
  unsigned b = __float_as_uint(v);
  return (ushort)((b + 0x7FFFu + ((b >> 16) & 1u)) >> 16);
}

// ---------------- init: zero degree + cursor ------------------------------
__global__ __launch_bounds__(256) void k_init(int* __restrict__ deg,
                                              int* __restrict__ cur) {
  int idx = blockIdx.x * 256 + threadIdx.x;
  if (idx < NN) { deg[idx] = 0; cur[idx] = 0; }
}

// ---------------- wq[r,d] = sum_o W[r,d,o] q[o]; same for k ---------------
__global__ __launch_bounds__(256) void k_wqk(const float* __restrict__ W,
    const float* __restrict__ qv, const float* __restrict__ kv,
    float* __restrict__ wq, float* __restrict__ wk) {
  int t = blockIdx.x * 256 + threadIdx.x;
  if (t >= RR * DD) return;
  int r = t / DD, d = t % DD;
  const float* row = W + ((size_t)r * DD + d) * DD;
  float aq = 0.f, ak = 0.f;
  for (int o = 0; o < DD; ++o) { float w = row[o]; aq += w * qv[o]; ak += w * kv[o]; }
  wq[t] = aq; wk[t] = ak;
}

// ---------------- nq[r,n] = x[n]·wq[r], one wave per node -----------------
__global__ __launch_bounds__(256) void k_nqk(const float* __restrict__ x,
    const float* __restrict__ wq, const float* __restrict__ wk,
    float* __restrict__ nq, float* __restrict__ nk) {
  int w = threadIdx.x >> 6, lane = threadIdx.x & 63;
  int n = blockIdx.x * 4 + w;
  if (n >= NN) return;
  float x0 = x[(size_t)n * DD + lane];
  float x1 = x[(size_t)n * DD + 64 + lane];
  for (int r = 0; r < RR; ++r) {
    float pq = x0 * wq[r * DD + lane] + x1 * wq[r * DD + 64 + lane];
    float pk = x0 * wk[r * DD + lane] + x1 * wk[r * DD + 64 + lane];
    #pragma unroll
    for (int m = 32; m > 0; m >>= 1) { pq += __shfl_xor(pq, m); pk += __shfl_xor(pk, m); }
    if (lane == 0) { nq[r * NN + n] = pq; nk[r * NN + n] = pk; }
  }
}

// ---------------- pack W into MFMA B-fragment order (bf16) ----------------
__global__ __launch_bounds__(256) void k_wpack(const float* __restrict__ W,
                                               ushort* __restrict__ wp) {
  int t = blockIdx.x * 256 + threadIdx.x;
  if (t >= RR * 8 * 4 * 64) return;
  int lane = t & 63;
  int ks = (t >> 6) & 3;
  int cf = (t >> 8) & 7;
  int r = t >> 11;
  int col = cf * 16 + (lane & 15);
  int k0 = ks * 32 + (lane >> 4) * 8;
  ushort* dst = wp + (size_t)t * 8;
  #pragma unroll
  for (int e = 0; e < 8; ++e)
    dst[e] = f2b(W[((size_t)r * DD + (k0 + e)) * DD + col]);
}

// ---------------- hx[r,n,o] via bf16 MFMA; A regs reused over relations ---
__global__ __launch_bounds__(256) void k_gemm(const float* __restrict__ x,
    const ushort* __restrict__ wp, ushort* __restrict__ hx) {
  int tid = threadIdx.x;
  int w = tid >> 6, l = tid & 63;
  int wrow = w & 1, wcol = w >> 1;
  int row0 = blockIdx.x * 64 + wrow * 32;
  int lr = l & 15, lg = l >> 4;

  short8 af[2][4];
  #pragma unroll
  for (int rf = 0; rf < 2; ++rf) {
    int row = row0 + rf * 16 + lr;
    row = row < NN ? row : NN - 1;
    const float* src = x + (size_t)row * DD + lg * 8;
    #pragma unroll
    for (int ks = 0; ks < 4; ++ks) {
      float4 u0 = *reinterpret_cast<const float4*>(src + ks * 32);
      float4 u1 = *reinterpret_cast<const float4*>(src + ks * 32 + 4);
      short8 a;
      a[0] = (short)f2b(u0.x); a[1] = (short)f2b(u0.y);
      a[2] = (short)f2b(u0.z); a[3] = (short)f2b(u0.w);
      a[4] = (short)f2b(u1.x); a[5] = (short)f2b(u1.y);
      a[6] = (short)f2b(u1.z); a[7] = (short)f2b(u1.w);
      af[rf][ks] = a;
    }
  }

  for (int r = 0; r < RR; ++r) {
    #pragma unroll
    for (int cfl = 0; cfl < 4; ++cfl) {
      int cfg = wcol * 4 + cfl;
      const ushort* bp = wp + (((size_t)(r * 8 + cfg) * 4) * 64 + l) * 8;
      short8 b0 = *reinterpret_cast<const short8*>(bp);
      short8 b1 = *reinterpret_cast<const short8*>(bp + 512);
      short8 b2 = *reinterpret_cast<const short8*>(bp + 1024);
      short8 b3 = *reinterpret_cast<const short8*>(bp + 1536);
      f32x4 acc0 = {0.f, 0.f, 0.f, 0.f};
      f32x4 acc1 = {0.f, 0.f, 0.f, 0.f};
      acc0 = __builtin_amdgcn_mfma_f32_16x16x32_bf16(af[0][0], b0, acc0, 0, 0, 0);
      acc1 = __builtin_amdgcn_mfma_f32_16x16x32_bf16(af[1][0], b0, acc1, 0, 0, 0);
      acc0 = __builtin_amdgcn_mfma_f32_16x16x32_bf16(af[0][1], b1, acc0, 0, 0, 0);
      acc1 = __builtin_amdgcn_mfma_f32_16x16x32_bf16(af[1][1], b1, acc1, 0, 0, 0);
      acc0 = __builtin_amdgcn_mfma_f32_16x16x32_bf16(af[0][2], b2, acc0, 0, 0, 0);
      acc1 = __builtin_amdgcn_mfma_f32_16x16x32_bf16(af[1][2], b2, acc1, 0, 0, 0);
      acc0 = __builtin_amdgcn_mfma_f32_16x16x32_bf16(af[0][3], b3, acc0, 0, 0, 0);
      acc1 = __builtin_amdgcn_mfma_f32_16x16x32_bf16(af[1][3], b3, acc1, 0, 0, 0);

      int col = cfg * 16 + lr;
      #pragma unroll
      for (int rf = 0; rf < 2; ++rf) {
        int rowb = row0 + rf * 16 + lg * 4;
        f32x4 ac = rf ? acc1 : acc0;
        #pragma unroll
        for (int j = 0; j < 4; ++j) {
          int rowz = rowb + j;
          if (rowz < NN)
            hx[((size_t)r * NN + rowz) * DD + col] = f2b(ac[j]);
        }
      }
    }
  }
}

// ---------------- histogram of destinations -------------------------------
__global__ __launch_bounds__(256) void k_hist(const int* __restrict__ ei,
                                              int* __restrict__ deg) {
  int e = blockIdx.x * 256 + threadIdx.x;
  if (e >= NE) return;
  atomicAdd(&deg[ei[NE + e]], 1);
}

// ---------------- exclusive scan (single block) ----------------------------
__global__ __launch_bounds__(1024) void k_scan(const int* __restrict__ deg,
                                               int* __restrict__ offs) {
  __shared__ int part[1024];
  int t = threadIdx.x;
  const int C = (NN + 1023) / 1024;
  int lo = t * C, hi = lo + C < NN ? lo + C : NN;
  int sum = 0;
  for (int i = lo; i < hi; ++i) sum += deg[i];
  part[t] = sum;
  __syncthreads();
  for (int off = 1; off < 1024; off <<= 1) {
    int u = (t >= off) ? part[t - off] : 0;
    __syncthreads();
    part[t] += u;
    __syncthreads();
  }
  int run = part[t] - sum;
  for (int i = lo; i < hi; ++i) { offs[i] = run; run += deg[i]; }
}

// ---------------- place edges into CSR slots (4B record only) --------------
__global__ __launch_bounds__(256) void k_place(const int* __restrict__ ei,
    const int* __restrict__ et, const int* __restrict__ offs,
    int* __restrict__ cur, int* __restrict__ rec_src) {
  int e = blockIdx.x * 256 + threadIdx.x;
  if (e >= NE) return;
  int s = ei[e], d = ei[NE + e], r = et[e];
  int pos = offs[d] + atomicAdd(&cur[d], 1);
  rec_src[pos] = s | (r << 20);
}

// ---------------- fused online-softmax gather-aggregate --------------------
// one 32-lane group per destination node; logits recomputed from nq/nk (L2)
__global__ __launch_bounds__(256) void k_agg(const float* __restrict__ x,
    const float* __restrict__ bias, const int* __restrict__ offs,
    const int* __restrict__ deg, const int* __restrict__ rec_src,
    const float* __restrict__ nq, const float* __restrict__ nk,
    const bf16* __restrict__ hx, float* __restrict__ out,
    float* __restrict__ mrec, float* __restrict__ irec) {
  int g = threadIdx.x >> 5, lane = threadIdx.x & 31;
  int n = blockIdx.x * 8 + g;
  if (n >= NN) return;
  int base = offs[n], cnt = deg[n];

  float m = -1e30f, ssum = 0.f;
  float a0 = 0.f, a1 = 0.f, a2 = 0.f, a3 = 0.f;

  int j = 0;
  for (; j + 1 < cnt; j += 2) {
    int sr1 = rec_src[base + j], sr2 = rec_src[base + j + 1];
    int s1 = sr1 & 0xFFFFF, r1 = sr1 >> 20;
    int s2 = sr2 & 0xFFFFF, r2 = sr2 >> 20;
    float l1 = nq[r1 * NN + n] + nk[r1 * NN + s1];
    float l2 = nq[r2 * NN + n] + nk[r2 * NN + s2];
    l1 = l1 > 0.f ? l1 : NEG * l1;
    l2 = l2 > 0.f ? l2 : NEG * l2;
    const bf16* row1 = hx + ((size_t)r1 * NN + s1) * DD + lane * 4;
    const bf16* row2 = hx + ((size_t)r2 * NN + s2) * DD + lane * 4;
    uint2 q1 = *reinterpret_cast<const uint2*>(row1);
    uint2 q2 = *reinterpret_cast<const uint2*>(row2);
    float mn = fmaxf(m, fmaxf(l1, l2));
    float sc = __expf(m - mn);
    float p1 = __expf(l1 - mn), p2 = __expf(l2 - mn);
    ssum = ssum * sc + p1 + p2;
    a0 = a0 * sc + p1 * bflo(q1.x) + p2 * bflo(q2.x);
    a1 = a1 * sc + p1 * bfhi(q1.x) + p2 * bfhi(q2.x);
    a2 = a2 * sc + p1 * bflo(q1.y) + p2 * bflo(q2.y);
    a3 = a3 * sc + p1 * bfhi(q1.y) + p2 * bfhi(q2.y);
    m = mn;
  }
  if (j < cnt) {
    int sr1 = rec_src[base + j];
    int s1 = sr1 & 0xFFFFF, r1 = sr1 >> 20;
    float l1 = nq[r1 * NN + n] + nk[r1 * NN + s1];
    l1 = l1 > 0.f ? l1 : NEG * l1;
    const bf16* row1 = hx + ((size_t)r1 * NN + s1) * DD + lane * 4;
    uint2 q1 = *reinterpret_cast<const uint2*>(row1);
    float mn = fmaxf(m, l1);
    float sc = __expf(m - mn);
    float p1 = __expf(l1 - mn);
    ssum = ssum * sc + p1;
    a0 = a0 * sc + p1 * bflo(q1.x);
    a1 = a1 * sc + p1 * bfhi(q1.x);
    a2 = a2 * sc + p1 * bflo(q1.y);
    a3 = a3 * sc + p1 * bfhi(q1.y);
    m = mn;
  }

  float inv = 1.f / (ssum + 1e-16f);
  size_t o = (size_t)n * DD + lane * 4;
  float4 xb = *reinterpret_cast<const float4*>(x + o);
  float4 bb = *reinterpret_cast<const float4*>(bias + lane * 4);
  float4 res;
  res.x = xb.x + bb.x + a0 * inv;
  res.y = xb.y + bb.y + a1 * inv;
  res.z = xb.z + bb.z + a2 * inv;
  res.w = xb.w + bb.w + a3 * inv;
  *reinterpret_cast<float4*>(out + o) = res;

  if (lane == 0) { mrec[n] = m; irec[n] = inv; }
}

// ---------------- alpha in original edge order (coalesced write) -----------
__global__ __launch_bounds__(256) void k_alpha(const int* __restrict__ ei,
    const int* __restrict__ et, const float* __restrict__ nq,
    const float* __restrict__ nk, const float* __restrict__ mrec,
    const float* __restrict__ irec, float* __restrict__ alpha) {
  int e = blockIdx.x * 256 + threadIdx.x;
  if (e >= NE) return;
  int s = ei[e], d = ei[NE + e], r = et[e];
  float l = nq[r * NN + d] + nk[r * NN + s];
  l = l > 0.f ? l : NEG * l;
  alpha[e] = __expf(l - mrec[d]) * irec[d];
}

extern "C" void kernel_launch(void* const* d_in, const int* in_sizes, int n_in,
                              void* d_out, int out_size, void* d_ws, size_t ws_size,
                              hipStream_t stream) {
  const float* x    = (const float*)d_in[0];
  const int*   ei   = (const int*)d_in[1];
  const int*   et   = (const int*)d_in[2];
  const float* W    = (const float*)d_in[3];
  const float* qv   = (const float*)d_in[4];
  const float* kv   = (const float*)d_in[5];
  const float* bias = (const float*)d_in[6];

  float* out   = (float*)d_out;              // [NN*DD]
  float* alpha = out + (size_t)NN * DD;      // [NE]

  char* p = (char*)d_ws;
  bf16*  hx        = (bf16*)p;        p += (size_t)RR * NN * DD * sizeof(bf16); // 76.8 MB
  float* nq        = (float*)p;       p += (size_t)RR * NN * sizeof(float);
  float* nk        = (float*)p;       p += (size_t)RR * NN * sizeof(float);
  float* wq        = (float*)p;       p += RR * DD * sizeof(float);
  float* wk        = (float*)p;       p += RR * DD * sizeof(float);
  int*   deg       = (int*)p;         p += NN * sizeof(int);
  int*   offs      = (int*)p;         p += NN * sizeof(int);
  int*   cur       = (int*)p;         p += NN * sizeof(int);
  float* mrec      = (float*)p;       p += NN * sizeof(float);
  float* irec      = (float*)p;       p += NN * sizeof(float);
  int*   rec_src   = (int*)p;         p += (size_t)NE * sizeof(int);
  ushort* wp       = (ushort*)p;      p += (size_t)RR * 8 * 4 * 64 * 8 * sizeof(ushort); // 197 KB

  k_init<<<(NN + 255) / 256, 256, 0, stream>>>(deg, cur);
  k_wqk<<<(RR * DD + 255) / 256, 256, 0, stream>>>(W, qv, kv, wq, wk);
  k_wpack<<<(RR * 8 * 4 * 64 + 255) / 256, 256, 0, stream>>>(W, wp);
  k_gemm<<<(NN + 63) / 64, 256, 0, stream>>>(x, wp, (ushort*)hx);
  k_nqk<<<(NN + 3) / 4, 256, 0, stream>>>(x, wq, wk, nq, nk);
  k_hist<<<(NE + 255) / 256, 256, 0, stream>>>(ei, deg);
  k_scan<<<1, 1024, 0, stream>>>(deg, offs);
  k_place<<<(NE + 255) / 256, 256, 0, stream>>>(ei, et, offs, cur, rec_src);
  k_agg<<<(NN + 7) / 8, 256, 0, stream>>>(x, bias, offs, deg, rec_src,
                                          nq, nk, hx, out, mrec, irec);
  k_alpha<<<(NE + 255) / 256, 256, 0, stream>>>(ei, et, nq, nk, mrec, irec, alpha);
}

// Round 5
// 250.219 us; speedup vs baseline: 1.4553x; 1.4553x over previous
//
#include <hip/hip_runtime.h>
#include <hip/hip_bf16.h>
#include <cstdint>

#define NN 50000
#define NE 1200000
#define DD 128
#define RR 6
#define NEG 0.2f
#define NB 196          // ceil(NN/256) buckets of 256 nodes
#define TILE 4096       // edges per k_bscatter block

typedef __hip_bfloat16 bf16;
typedef __attribute__((ext_vector_type(8))) short short8;
typedef __attribute__((ext_vector_type(4))) float f32x4;

__device__ __forceinline__ float bflo(unsigned u) { return __uint_as_float((u & 0xFFFFu) << 16); }
__device__ __forceinline__ float bfhi(unsigned u) { return __uint_as_float(u & 0xFFFF0000u); }
__device__ __forceinline__ ushort f2b(float v) {  // f32 -> bf16 RTNE
  unsigned b = __float_as_uint(v);
  return (ushort)((b + 0x7FFFu + ((b >> 16) & 1u)) >> 16);
}

// ---------------- init: zero bucket counters ------------------------------
__global__ __launch_bounds__(256) void k_init(int* __restrict__ bcnt) {
  int idx = threadIdx.x;
  if (idx < NB) bcnt[idx] = 0;
}

// ---------------- wq[r,d] = sum_o W[r,d,o] q[o]; same for k ---------------
__global__ __launch_bounds__(256) void k_wqk(const float* __restrict__ W,
    const float* __restrict__ qv, const float* __restrict__ kv,
    float* __restrict__ wq, float* __restrict__ wk) {
  int t = blockIdx.x * 256 + threadIdx.x;
  if (t >= RR * DD) return;
  int r = t / DD, d = t % DD;
  const float* row = W + ((size_t)r * DD + d) * DD;
  float aq = 0.f, ak = 0.f;
  for (int o = 0; o < DD; ++o) { float w = row[o]; aq += w * qv[o]; ak += w * kv[o]; }
  wq[t] = aq; wk[t] = ak;
}

// ---------------- nq[r,n] = x[n]·wq[r], one wave per node -----------------
__global__ __launch_bounds__(256) void k_nqk(const float* __restrict__ x,
    const float* __restrict__ wq, const float* __restrict__ wk,
    float* __restrict__ nq, float* __restrict__ nk) {
  int w = threadIdx.x >> 6, lane = threadIdx.x & 63;
  int n = blockIdx.x * 4 + w;
  if (n >= NN) return;
  float x0 = x[(size_t)n * DD + lane];
  float x1 = x[(size_t)n * DD + 64 + lane];
  for (int r = 0; r < RR; ++r) {
    float pq = x0 * wq[r * DD + lane] + x1 * wq[r * DD + 64 + lane];
    float pk = x0 * wk[r * DD + lane] + x1 * wk[r * DD + 64 + lane];
    #pragma unroll
    for (int m = 32; m > 0; m >>= 1) { pq += __shfl_xor(pq, m); pk += __shfl_xor(pk, m); }
    if (lane == 0) { nq[r * NN + n] = pq; nk[r * NN + n] = pk; }
  }
}

// ---------------- pack W into MFMA B-fragment order (bf16) ----------------
__global__ __launch_bounds__(256) void k_wpack(const float* __restrict__ W,
                                               ushort* __restrict__ wp) {
  int t = blockIdx.x * 256 + threadIdx.x;
  if (t >= RR * 8 * 4 * 64) return;
  int lane = t & 63;
  int ks = (t >> 6) & 3;
  int cf = (t >> 8) & 7;
  int r = t >> 11;
  int col = cf * 16 + (lane & 15);
  int k0 = ks * 32 + (lane >> 4) * 8;
  ushort* dst = wp + (size_t)t * 8;
  #pragma unroll
  for (int e = 0; e < 8; ++e)
    dst[e] = f2b(W[((size_t)r * DD + (k0 + e)) * DD + col]);
}

// ---------------- hx[r,n,o] via bf16 MFMA; A regs reused over relations ---
__global__ __launch_bounds__(256) void k_gemm(const float* __restrict__ x,
    const ushort* __restrict__ wp, ushort* __restrict__ hx) {
  int tid = threadIdx.x;
  int w = tid >> 6, l = tid & 63;
  int wrow = w & 1, wcol = w >> 1;
  int row0 = blockIdx.x * 64 + wrow * 32;
  int lr = l & 15, lg = l >> 4;

  short8 af[2][4];
  #pragma unroll
  for (int rf = 0; rf < 2; ++rf) {
    int row = row0 + rf * 16 + lr;
    row = row < NN ? row : NN - 1;
    const float* src = x + (size_t)row * DD + lg * 8;
    #pragma unroll
    for (int ks = 0; ks < 4; ++ks) {
      float4 u0 = *reinterpret_cast<const float4*>(src + ks * 32);
      float4 u1 = *reinterpret_cast<const float4*>(src + ks * 32 + 4);
      short8 a;
      a[0] = (short)f2b(u0.x); a[1] = (short)f2b(u0.y);
      a[2] = (short)f2b(u0.z); a[3] = (short)f2b(u0.w);
      a[4] = (short)f2b(u1.x); a[5] = (short)f2b(u1.y);
      a[6] = (short)f2b(u1.z); a[7] = (short)f2b(u1.w);
      af[rf][ks] = a;
    }
  }

  for (int r = 0; r < RR; ++r) {
    #pragma unroll
    for (int cfl = 0; cfl < 4; ++cfl) {
      int cfg = wcol * 4 + cfl;
      const ushort* bp = wp + (((size_t)(r * 8 + cfg) * 4) * 64 + l) * 8;
      short8 b0 = *reinterpret_cast<const short8*>(bp);
      short8 b1 = *reinterpret_cast<const short8*>(bp + 512);
      short8 b2 = *reinterpret_cast<const short8*>(bp + 1024);
      short8 b3 = *reinterpret_cast<const short8*>(bp + 1536);
      f32x4 acc0 = {0.f, 0.f, 0.f, 0.f};
      f32x4 acc1 = {0.f, 0.f, 0.f, 0.f};
      acc0 = __builtin_amdgcn_mfma_f32_16x16x32_bf16(af[0][0], b0, acc0, 0, 0, 0);
      acc1 = __builtin_amdgcn_mfma_f32_16x16x32_bf16(af[1][0], b0, acc1, 0, 0, 0);
      acc0 = __builtin_amdgcn_mfma_f32_16x16x32_bf16(af[0][1], b1, acc0, 0, 0, 0);
      acc1 = __builtin_amdgcn_mfma_f32_16x16x32_bf16(af[1][1], b1, acc1, 0, 0, 0);
      acc0 = __builtin_amdgcn_mfma_f32_16x16x32_bf16(af[0][2], b2, acc0, 0, 0, 0);
      acc1 = __builtin_amdgcn_mfma_f32_16x16x32_bf16(af[1][2], b2, acc1, 0, 0, 0);
      acc0 = __builtin_amdgcn_mfma_f32_16x16x32_bf16(af[0][3], b3, acc0, 0, 0, 0);
      acc1 = __builtin_amdgcn_mfma_f32_16x16x32_bf16(af[1][3], b3, acc1, 0, 0, 0);

      int col = cfg * 16 + lr;
      #pragma unroll
      for (int rf = 0; rf < 2; ++rf) {
        int rowb = row0 + rf * 16 + lg * 4;
        f32x4 ac = rf ? acc1 : acc0;
        #pragma unroll
        for (int j = 0; j < 4; ++j) {
          int rowz = rowb + j;
          if (rowz < NN)
            hx[((size_t)r * NN + rowz) * DD + col] = f2b(ac[j]);
        }
      }
    }
  }
}

// ---------------- bucket histogram (LDS-staged) ----------------------------
__global__ __launch_bounds__(256) void k_histb(const int* __restrict__ ei,
                                               int* __restrict__ bcnt) {
  __shared__ int lh[NB];
  int tid = threadIdx.x;
  if (tid < NB) lh[tid] = 0;
  __syncthreads();
  int e = blockIdx.x * 1024 + tid;
  #pragma unroll
  for (int k = 0; k < 4; ++k, e += 256)
    if (e < NE) atomicAdd(&lh[ei[NE + e] >> 8], 1);
  __syncthreads();
  if (tid < NB && lh[tid]) atomicAdd(&bcnt[tid], lh[tid]);
}

// ---------------- bucket base scan + zero cursors --------------------------
__global__ __launch_bounds__(64) void k_bscan(const int* __restrict__ bcnt,
    int* __restrict__ bbase, int* __restrict__ bcur) {
  if (threadIdx.x == 0) {
    int run = 0;
    for (int i = 0; i < NB; ++i) { bbase[i] = run; bcur[i] = 0; run += bcnt[i]; }
  }
}

// ---------------- partition edges into bucket-grouped bedge ----------------
__global__ __launch_bounds__(256) void k_bscatter(const int* __restrict__ ei,
    const int* __restrict__ et, const int* __restrict__ bbase,
    int* __restrict__ bcur, uint2* __restrict__ bedge) {
  __shared__ int sval[TILE];
  __shared__ unsigned short sdst[TILE];
  __shared__ int lh[NB], lbase[NB], lcur[NB];
  int tid = threadIdx.x;
  int e0 = blockIdx.x * TILE;
  int lim = NE - e0; if (lim > TILE) lim = TILE;
  for (int i = tid; i < NB; i += 256) lh[i] = 0;
  __syncthreads();
  for (int i = tid; i < lim; i += 256) {
    int e = e0 + i;
    int d = ei[NE + e];
    sval[i] = ei[e] | (et[e] << 20);
    sdst[i] = (unsigned short)d;
    atomicAdd(&lh[d >> 8], 1);
  }
  __syncthreads();
  for (int i = tid; i < NB; i += 256) {
    int c = lh[i];
    lbase[i] = c ? atomicAdd(&bcur[i], c) : 0;
    lcur[i] = 0;
  }
  __syncthreads();
  for (int i = tid; i < lim; i += 256) {
    int d = sdst[i];
    int b = d >> 8;
    int pos = bbase[b] + lbase[b] + atomicAdd(&lcur[b], 1);
    bedge[pos] = make_uint2((unsigned)sval[i], (unsigned)d);
  }
}

// ---------------- per-bucket: deg, offs, CSR placement (L2-local writes) ---
__global__ __launch_bounds__(256) void k_bfinal(const uint2* __restrict__ bedge,
    const int* __restrict__ bbase, const int* __restrict__ bcnt,
    int* __restrict__ deg, int* __restrict__ offs, int* __restrict__ rec_src) {
  __shared__ int lh[256], sc[256], lcur[256];
  int b = blockIdx.x, tid = threadIdx.x;
  int base = bbase[b], cnt = bcnt[b];
  lh[tid] = 0;
  __syncthreads();
  for (int i = tid; i < cnt; i += 256)
    atomicAdd(&lh[bedge[base + i].y & 255], 1);
  __syncthreads();
  int v = lh[tid];
  sc[tid] = v;
  __syncthreads();
  for (int off = 1; off < 256; off <<= 1) {
    int u = (tid >= off) ? sc[tid - off] : 0;
    __syncthreads();
    sc[tid] += u;
    __syncthreads();
  }
  int excl = sc[tid] - v;
  int n = (b << 8) + tid;
  if (n < NN) { deg[n] = v; offs[n] = base + excl; }
  lcur[tid] = base + excl;
  __syncthreads();
  for (int i = tid; i < cnt; i += 256) {
    uint2 r = bedge[base + i];
    int pos = atomicAdd(&lcur[r.y & 255], 1);
    rec_src[pos] = (int)r.x;
  }
}

// ---------------- fused online-softmax gather-aggregate --------------------
__global__ __launch_bounds__(256) void k_agg(const float* __restrict__ x,
    const float* __restrict__ bias, const int* __restrict__ offs,
    const int* __restrict__ deg, const int* __restrict__ rec_src,
    const float* __restrict__ nq, const float* __restrict__ nk,
    const bf16* __restrict__ hx, float* __restrict__ out,
    float* __restrict__ mrec, float* __restrict__ irec) {
  int g = threadIdx.x >> 5, lane = threadIdx.x & 31;
  int n = blockIdx.x * 8 + g;
  if (n >= NN) return;
  int base = offs[n], cnt = deg[n];

  float m = -1e30f, ssum = 0.f;
  float a0 = 0.f, a1 = 0.f, a2 = 0.f, a3 = 0.f;

  int j = 0;
  for (; j + 1 < cnt; j += 2) {
    int sr1 = rec_src[base + j], sr2 = rec_src[base + j + 1];
    int s1 = sr1 & 0xFFFFF, r1 = sr1 >> 20;
    int s2 = sr2 & 0xFFFFF, r2 = sr2 >> 20;
    float l1 = nq[r1 * NN + n] + nk[r1 * NN + s1];
    float l2 = nq[r2 * NN + n] + nk[r2 * NN + s2];
    l1 = l1 > 0.f ? l1 : NEG * l1;
    l2 = l2 > 0.f ? l2 : NEG * l2;
    const bf16* row1 = hx + ((size_t)r1 * NN + s1) * DD + lane * 4;
    const bf16* row2 = hx + ((size_t)r2 * NN + s2) * DD + lane * 4;
    uint2 q1 = *reinterpret_cast<const uint2*>(row1);
    uint2 q2 = *reinterpret_cast<const uint2*>(row2);
    float mn = fmaxf(m, fmaxf(l1, l2));
    float sc = __expf(m - mn);
    float p1 = __expf(l1 - mn), p2 = __expf(l2 - mn);
    ssum = ssum * sc + p1 + p2;
    a0 = a0 * sc + p1 * bflo(q1.x) + p2 * bflo(q2.x);
    a1 = a1 * sc + p1 * bfhi(q1.x) + p2 * bfhi(q2.x);
    a2 = a2 * sc + p1 * bflo(q1.y) + p2 * bflo(q2.y);
    a3 = a3 * sc + p1 * bfhi(q1.y) + p2 * bfhi(q2.y);
    m = mn;
  }
  if (j < cnt) {
    int sr1 = rec_src[base + j];
    int s1 = sr1 & 0xFFFFF, r1 = sr1 >> 20;
    float l1 = nq[r1 * NN + n] + nk[r1 * NN + s1];
    l1 = l1 > 0.f ? l1 : NEG * l1;
    const bf16* row1 = hx + ((size_t)r1 * NN + s1) * DD + lane * 4;
    uint2 q1 = *reinterpret_cast<const uint2*>(row1);
    float mn = fmaxf(m, l1);
    float sc = __expf(m - mn);
    float p1 = __expf(l1 - mn);
    ssum = ssum * sc + p1;
    a0 = a0 * sc + p1 * bflo(q1.x);
    a1 = a1 * sc + p1 * bfhi(q1.x);
    a2 = a2 * sc + p1 * bflo(q1.y);
    a3 = a3 * sc + p1 * bfhi(q1.y);
    m = mn;
  }

  float inv = 1.f / (ssum + 1e-16f);
  size_t o = (size_t)n * DD + lane * 4;
  float4 xb = *reinterpret_cast<const float4*>(x + o);
  float4 bb = *reinterpret_cast<const float4*>(bias + lane * 4);
  float4 res;
  res.x = xb.x + bb.x + a0 * inv;
  res.y = xb.y + bb.y + a1 * inv;
  res.z = xb.z + bb.z + a2 * inv;
  res.w = xb.w + bb.w + a3 * inv;
  *reinterpret_cast<float4*>(out + o) = res;

  if (lane == 0) { mrec[n] = m; irec[n] = inv; }
}

// ---------------- alpha in original edge order (coalesced write) -----------
__global__ __launch_bounds__(256) void k_alpha(const int* __restrict__ ei,
    const int* __restrict__ et, const float* __restrict__ nq,
    const float* __restrict__ nk, const float* __restrict__ mrec,
    const float* __restrict__ irec, float* __restrict__ alpha) {
  int e = blockIdx.x * 256 + threadIdx.x;
  if (e >= NE) return;
  int s = ei[e], d = ei[NE + e], r = et[e];
  float l = nq[r * NN + d] + nk[r * NN + s];
  l = l > 0.f ? l : NEG * l;
  alpha[e] = __expf(l - mrec[d]) * irec[d];
}

extern "C" void kernel_launch(void* const* d_in, const int* in_sizes, int n_in,
                              void* d_out, int out_size, void* d_ws, size_t ws_size,
                              hipStream_t stream) {
  const float* x    = (const float*)d_in[0];
  const int*   ei   = (const int*)d_in[1];
  const int*   et   = (const int*)d_in[2];
  const float* W    = (const float*)d_in[3];
  const float* qv   = (const float*)d_in[4];
  const float* kv   = (const float*)d_in[5];
  const float* bias = (const float*)d_in[6];

  float* out   = (float*)d_out;              // [NN*DD]
  float* alpha = out + (size_t)NN * DD;      // [NE]

  char* p = (char*)d_ws;
  bf16*  hx      = (bf16*)p;    p += (size_t)RR * NN * DD * sizeof(bf16); // 76.8 MB
  float* nq      = (float*)p;   p += (size_t)RR * NN * sizeof(float);
  float* nk      = (float*)p;   p += (size_t)RR * NN * sizeof(float);
  float* wq      = (float*)p;   p += RR * DD * sizeof(float);
  float* wk      = (float*)p;   p += RR * DD * sizeof(float);
  int*   deg     = (int*)p;     p += NN * sizeof(int);
  int*   offs    = (int*)p;     p += NN * sizeof(int);
  float* mrec    = (float*)p;   p += NN * sizeof(float);
  float* irec    = (float*)p;   p += NN * sizeof(float);
  int*   bcnt    = (int*)p;     p += NB * sizeof(int);
  int*   bbase   = (int*)p;     p += NB * sizeof(int);
  int*   bcur    = (int*)p;     p += NB * sizeof(int);
  p = (char*)(((uintptr_t)p + 15) & ~(uintptr_t)15);
  uint2* bedge   = (uint2*)p;   p += (size_t)NE * sizeof(uint2);          // 9.6 MB
  int*   rec_src = (int*)p;     p += (size_t)NE * sizeof(int);            // 4.8 MB
  ushort* wp     = (ushort*)p;  p += (size_t)RR * 8 * 4 * 64 * 8 * sizeof(ushort); // 197 KB

  k_init<<<1, 256, 0, stream>>>(bcnt);
  k_wqk<<<(RR * DD + 255) / 256, 256, 0, stream>>>(W, qv, kv, wq, wk);
  k_wpack<<<(RR * 8 * 4 * 64 + 255) / 256, 256, 0, stream>>>(W, wp);
  k_gemm<<<(NN + 63) / 64, 256, 0, stream>>>(x, wp, (ushort*)hx);
  k_nqk<<<(NN + 3) / 4, 256, 0, stream>>>(x, wq, wk, nq, nk);
  k_histb<<<(NE + 1023) / 1024, 256, 0, stream>>>(ei, bcnt);
  k_bscan<<<1, 64, 0, stream>>>(bcnt, bbase, bcur);
  k_bscatter<<<(NE + TILE - 1) / TILE, 256, 0, stream>>>(ei, et, bbase, bcur, bedge);
  k_bfinal<<<NB, 256, 0, stream>>>(bedge, bbase, bcnt, deg, offs, rec_src);
  k_agg<<<(NN + 7) / 8, 256, 0, stream>>>(x, bias, offs, deg, rec_src,
                                          nq, nk, hx, out, mrec, irec);
  k_alpha<<<(NE + 255) / 256, 256, 0, stream>>>(ei, et, nq, nk, mrec, irec, alpha);
}